// Round 9
// baseline (211.512 us; speedup 1.0000x reference)
//
#include <hip/hip_runtime.h>

#define NGRP 512        // dst-range groups; requires n <= 131072 (SRC_BITS) and GN <= 512
#define CAP  6656       // per-group edge capacity (E/NGRP=6250 + 5 sigma)
#define EPB  8192       // edges per partition block
#define NE   16         // edges register-cached per thread (EPB/512)
#define SRC_BITS 17
#define SRC_MASK 0x1FFFF

// ---- bf16 helpers (manual, RNE) ----
static __device__ __forceinline__ unsigned short f2bf(float f) {
    unsigned u = __float_as_uint(f);
    return (unsigned short)((u + 0x7FFFu + ((u >> 16) & 1u)) >> 16);
}
static __device__ __forceinline__ float bf2f_lo(unsigned u) { return __uint_as_float(u << 16); }
static __device__ __forceinline__ float bf2f_hi(unsigned u) { return __uint_as_float(u & 0xFFFF0000u); }

// ---------------- CSR build ----------------

__global__ void k_init(int* gcursor) {
    gcursor[threadIdx.x] = threadIdx.x * CAP;   // 512 threads
}

// single global read of ei: register-cache NE edges/thread across hist+scatter passes
__global__ __launch_bounds__(512) void k_partition(const int* __restrict__ ei, int* gcursor,
                                                   unsigned* __restrict__ pairs,
                                                   int E, int n, int GN) {
    __shared__ int cnt[NGRP];
    __shared__ int cur[NGRP];
    int tid = threadIdx.x;
    cnt[tid] = 0;
    __syncthreads();
    int base = blockIdx.x * EPB;
    int sreg[NE], dreg[NE];
#pragma unroll
    for (int k = 0; k < NE; ++k) {
        int e = base + tid + k * 512;    // coalesced
        int d = -1, s = 0;
        if (e < E) {
            s = ei[e];
            d = ei[E + e];
            if ((unsigned)s < (unsigned)n && (unsigned)d < (unsigned)n)
                atomicAdd(&cnt[d / GN], 1);
            else d = -1;
        }
        sreg[k] = s; dreg[k] = d;
    }
    __syncthreads();
    { int c = cnt[tid]; cur[tid] = c ? atomicAdd(&gcursor[tid], c) : 0; }
    __syncthreads();
#pragma unroll
    for (int k = 0; k < NE; ++k) {
        int d = dreg[k];
        if (d >= 0) {
            int g = d / GN;
            int w = atomicAdd(&cur[g], 1);
            if (w < (g + 1) * CAP)   // capacity guard: drop -> loud absmax fail, no corruption
                pairs[w] = ((unsigned)(d - g * GN) << SRC_BITS) | (unsigned)sreg[k];
        }
    }
}

// one 512-thread block per group: LDS-stage pairs, hist, scan -> rowStart/rowEnd/dinv/z,
// then scatter srclist within the group's window
__global__ __launch_bounds__(512) void k_build(const int* __restrict__ gcursor,
                                               const unsigned* __restrict__ pairs,
                                               const float2* __restrict__ x2,
                                               int* __restrict__ rowStart, int* __restrict__ rowEnd,
                                               int* __restrict__ srclist, float* __restrict__ dinv,
                                               float2* __restrict__ z, int n, int GN) {
    __shared__ unsigned pl[CAP];
    __shared__ int cnt[512];
    __shared__ int cur[512];
    int g = blockIdx.x;
    int t = threadIdx.x;
    int gbeg = g * CAP;
    int gend = gcursor[g];
    int cape = gbeg + CAP;
    if (gend > cape) gend = cape;
    int m = gend - gbeg;
    cnt[t] = 0;
    __syncthreads();
    for (int k = t; k < m; k += 512) {
        unsigned v = pairs[gbeg + k];
        pl[k] = v;
        atomicAdd(&cnt[(v >> SRC_BITS) & 511], 1);
    }
    __syncthreads();
    int c = cnt[t];
    for (int off = 1; off < 512; off <<= 1) {
        int add = (t >= off) ? cnt[t - off] : 0;
        __syncthreads();
        cnt[t] += add;
        __syncthreads();
    }
    int excl = cnt[t] - c;
    int node = g * GN + t;
    if (t < GN && node < n) {
        int st = gbeg + excl;
        rowStart[node] = st;
        rowEnd[node] = st + c;
        float di = rsqrtf(1.0f + (float)c);
        dinv[node] = di;
        float2 xv = x2[node];
        z[node] = make_float2(xv.x * di, xv.y * di);
    }
    cur[t] = excl;
    __syncthreads();
    for (int k = t; k < m; k += 512) {
        unsigned v = pl[k];
        int dl = (v >> SRC_BITS) & 511;
        int pos = atomicAdd(&cur[dl], 1);
        srclist[gbeg + pos] = (int)(v & SRC_MASK);
    }
}

// ---------------- GCN compute ----------------

// conv1 aggregation on raw 2-feature rows: agg[i] = z[i] + sum_{s->i} z[s]
__global__ void k_gather2f(const int* __restrict__ rowStart, const int* __restrict__ rowEnd,
                           const int* __restrict__ srclist, const float2* __restrict__ z,
                           float2* __restrict__ agg, int n) {
    int w = blockIdx.x * (blockDim.x >> 6) + (threadIdx.x >> 6);
    if (w >= n) return;
    int lane = threadIdx.x & 63;
    int start = rowStart[w], end = rowEnd[w];
    float ax = 0.f, ay = 0.f;
    for (int e = start + lane; e < end; e += 64) {
        int s = srclist[e];
        float2 v = z[s];
        ax += v.x; ay += v.y;
    }
#pragma unroll
    for (int m = 1; m < 64; m <<= 1) {
        ax += __shfl_xor(ax, m, 64);
        ay += __shfl_xor(ay, m, 64);
    }
    if (lane == 0) {
        float2 v = z[w];   // self-loop
        agg[w] = make_float2(ax + v.x, ay + v.y);
    }
}

// h1 = relu(dinv*(agg@W1) + b1); y = bf16((h1 @ W2) * dinv) into two feature planes
__global__ void k_mid1(const float2* __restrict__ agg, const float* __restrict__ dinv,
                       const float* __restrict__ W1, const float* __restrict__ b1,
                       const float* __restrict__ W2, unsigned short* __restrict__ y0,
                       unsigned short* __restrict__ y1, int n) {
    __shared__ float sW[1024];
    __shared__ float sh[8][33];
    int tid = threadIdx.x;
    for (int k = tid; k < 1024; k += 256) sW[k] = W2[k];
    int ln = tid >> 5, f = tid & 31;
    int i = blockIdx.x * 8 + ln;
    float h = 0.f, di = 0.f;
    if (i < n) {
        di = dinv[i];
        float2 a = agg[i];
        h = di * (a.x * W1[f] + a.y * W1[32 + f]) + b1[f];
        h = h > 0.f ? h : 0.f;
    }
    sh[ln][f] = h;
    __syncthreads();
    if (i < n) {
        float acc = 0.f;
#pragma unroll
        for (int k = 0; k < 32; ++k) acc += sh[ln][k] * sW[k * 32 + f];
        unsigned short* yp = (f < 16) ? y0 : y1;
        yp[(size_t)i * 16 + (f & 15)] = f2bf(acc * di);
    }
}

// conv2 gather, one 16-feature plane per pass: 32 edge-slots x 2 lanes, uint4 per lane.
// Working set 3.2MB fits per-XCD L2.
__global__ void k_gather_half(const int* __restrict__ rowStart, const int* __restrict__ rowEnd,
                              const int* __restrict__ srclist, const uint4* __restrict__ yh,
                              float4* __restrict__ acc4, int n, int p) {
    int w = blockIdx.x * (blockDim.x >> 6) + (threadIdx.x >> 6);
    if (w >= n) return;
    int lane = threadIdx.x & 63;
    int slot = lane >> 1, q = lane & 1;
    int start = rowStart[w], end = rowEnd[w];
    float a0 = 0.f, a1 = 0.f, a2 = 0.f, a3 = 0.f, a4 = 0.f, a5 = 0.f, a6 = 0.f, a7 = 0.f;
    for (int e = start + slot; e < end; e += 32) {
        int s = srclist[e];
        uint4 v = yh[(size_t)s * 2 + q];
        a0 += bf2f_lo(v.x); a1 += bf2f_hi(v.x);
        a2 += bf2f_lo(v.y); a3 += bf2f_hi(v.y);
        a4 += bf2f_lo(v.z); a5 += bf2f_hi(v.z);
        a6 += bf2f_lo(v.w); a7 += bf2f_hi(v.w);
    }
#pragma unroll
    for (int m = 2; m < 64; m <<= 1) {
        a0 += __shfl_xor(a0, m, 64);
        a1 += __shfl_xor(a1, m, 64);
        a2 += __shfl_xor(a2, m, 64);
        a3 += __shfl_xor(a3, m, 64);
        a4 += __shfl_xor(a4, m, 64);
        a5 += __shfl_xor(a5, m, 64);
        a6 += __shfl_xor(a6, m, 64);
        a7 += __shfl_xor(a7, m, 64);
    }
    if (slot == 0) {   // lanes 0,1
        uint4 v = yh[(size_t)w * 2 + q];  // self-loop
        a0 += bf2f_lo(v.x); a1 += bf2f_hi(v.x);
        a2 += bf2f_lo(v.y); a3 += bf2f_hi(v.y);
        a4 += bf2f_lo(v.z); a5 += bf2f_hi(v.z);
        a6 += bf2f_lo(v.w); a7 += bf2f_hi(v.w);
        float4* dst = acc4 + (size_t)w * 8 + p * 4 + q * 2;
        dst[0] = make_float4(a0, a1, a2, a3);
        dst[1] = make_float4(a4, a5, a6, a7);
    }
}

// h2 = relu(dinv*acc + b2); h3 = relu(h2 @ Wf1 + bf1); out = h3 . Wf2 + bf2
__global__ void k_final(const float* __restrict__ acc, const float* __restrict__ dinv,
                        const float* __restrict__ b2, const float* __restrict__ Wf1,
                        const float* __restrict__ bf1, const float* __restrict__ Wf2,
                        const float* __restrict__ bf2, float* __restrict__ out, int n) {
    __shared__ float sW[1024];
    __shared__ float sh[8][33];
    int tid = threadIdx.x;
    for (int k = tid; k < 1024; k += 256) sW[k] = Wf1[k];
    int ln = tid >> 5, f = tid & 31;
    int i = blockIdx.x * 8 + ln;
    float h = 0.f;
    if (i < n) {
        h = dinv[i] * acc[(size_t)i * 32 + f] + b2[f];
        h = h > 0.f ? h : 0.f;
    }
    sh[ln][f] = h;
    __syncthreads();
    float p = 0.f;
    if (i < n) {
        float a = bf1[f];
#pragma unroll
        for (int k = 0; k < 32; ++k) a += sh[ln][k] * sW[k * 32 + f];
        a = a > 0.f ? a : 0.f;
        p = a * Wf2[f];
    }
#pragma unroll
    for (int m = 16; m >= 1; m >>= 1) p += __shfl_xor(p, m, 64);
    if (f == 0 && i < n) out[i] = p + bf2[0];
}

// ---------------- launch ----------------

extern "C" void kernel_launch(void* const* d_in, const int* in_sizes, int n_in,
                              void* d_out, int out_size, void* d_ws, size_t ws_size,
                              hipStream_t stream) {
    const float* x   = (const float*)d_in[0];
    const int*   ei  = (const int*)d_in[1];
    const float* W1  = (const float*)d_in[2];
    const float* b1  = (const float*)d_in[3];
    const float* W2  = (const float*)d_in[4];
    const float* b2  = (const float*)d_in[5];
    const float* Wf1 = (const float*)d_in[6];
    const float* bf1 = (const float*)d_in[7];
    const float* Wf2 = (const float*)d_in[8];
    const float* bf2 = (const float*)d_in[9];
    float* out = (float*)d_out;

    int n = in_sizes[0] / 2;   // x is [N,2]; n=100000 (<=131072)
    int E = in_sizes[1] / 2;   // edge_index is [2,E]
    int GN = (n + NGRP - 1) / NGRP;   // 196 nodes per group

    // workspace layout (float offsets; all even -> float2/uint4 alignment holds)
    float* wsf = (float*)d_ws;
    int*    srclist  = (int*)wsf;                          // NGRP*CAP ints
    size_t  o = (size_t)NGRP * CAP;
    int*    rowStart = (int*)(wsf + o);     o += n;        // n
    int*    rowEnd   = (int*)(wsf + o);     o += n;        // n
    float*  dinv     = wsf + o;             o += n;        // n
    float2* z        = (float2*)(wsf + o);  o += 2 * (size_t)n;   // n float2
    float2* agg      = (float2*)(wsf + o);  o += 2 * (size_t)n;   // n float2
    int*    gcursor  = (int*)(wsf + o);     o += NGRP;     // 512
    o = (o + 3) & ~(size_t)3;                              // 16B align
    float*  acc      = wsf + o;             o += 32 * (size_t)n;  // 32n floats
    unsigned short* y0 = (unsigned short*)(wsf + o);       // 16n bf16 (8n floats)
    unsigned short* y1 = y0 + (size_t)n * 16;              // 16n bf16
    // pairs (NGRP*CAP u32 = 13.6MB) aliases acc (+ start of y0); consumed by k_build
    // before acc (gather) or y planes (mid1) are written.
    unsigned* pairs = (unsigned*)acc;

    const int B = 256;
    int nblk = (E + EPB - 1) / EPB;

    // CSR build — zero per-edge global atomics, single ei read
    k_init<<<1, NGRP, 0, stream>>>(gcursor);
    k_partition<<<nblk, 512, 0, stream>>>(ei, gcursor, pairs, E, n, GN);
    k_build<<<NGRP, 512, 0, stream>>>(gcursor, pairs, (const float2*)x, rowStart, rowEnd,
                                      srclist, dinv, z, n, GN);

    // conv1: aggregate 2-feature z rows, then fused (agg@W1 -> relu -> @W2 -> scale)
    k_gather2f<<<(n + 3) / 4, B, 0, stream>>>(rowStart, rowEnd, srclist, z, agg, n);
    k_mid1<<<(n + 7) / 8, B, 0, stream>>>(agg, dinv, W1, b1, W2, y0, y1, n);

    // conv2: two L2-resident half-feature gathers
    k_gather_half<<<(n + 3) / 4, B, 0, stream>>>(rowStart, rowEnd, srclist, (const uint4*)y0,
                                                 (float4*)acc, n, 0);
    k_gather_half<<<(n + 3) / 4, B, 0, stream>>>(rowStart, rowEnd, srclist, (const uint4*)y1,
                                                 (float4*)acc, n, 1);

    // conv2 finalize + MLP head
    k_final<<<(n + 7) / 8, B, 0, stream>>>(acc, dinv, b2, Wf1, bf1, Wf2, bf2, out, n);
}

// Round 10
// 179.782 us; speedup vs baseline: 1.1765x; 1.1765x over previous
//
#include <hip/hip_runtime.h>

#define NGRP 512        // dst-range groups; requires n <= 131072 (SRC_BITS) and GN <= 512
#define CAP  6656       // per-group edge capacity (E/NGRP=6250 + 5 sigma)
#define EPB  8192       // edges per partition block
#define NE   16         // edges register-cached per thread (EPB/512)
#define SRC_BITS 17
#define SRC_MASK 0x1FFFF

// ---- bf16 helpers (manual, RNE) ----
static __device__ __forceinline__ unsigned short f2bf(float f) {
    unsigned u = __float_as_uint(f);
    return (unsigned short)((u + 0x7FFFu + ((u >> 16) & 1u)) >> 16);
}
static __device__ __forceinline__ float bf2f_lo(unsigned u) { return __uint_as_float(u << 16); }
static __device__ __forceinline__ float bf2f_hi(unsigned u) { return __uint_as_float(u & 0xFFFF0000u); }

// ---------------- CSR build ----------------

__global__ void k_init(int* gcursor) {
    gcursor[threadIdx.x] = threadIdx.x * CAP;   // 512 threads
}

// single global read of ei: register-cache NE edges/thread across hist+scatter passes
__global__ __launch_bounds__(512) void k_partition(const int* __restrict__ ei, int* gcursor,
                                                   unsigned* __restrict__ pairs,
                                                   int E, int n, int GN) {
    __shared__ int cnt[NGRP];
    __shared__ int cur[NGRP];
    int tid = threadIdx.x;
    cnt[tid] = 0;
    __syncthreads();
    int base = blockIdx.x * EPB;
    int sreg[NE], dreg[NE];
#pragma unroll
    for (int k = 0; k < NE; ++k) {
        int e = base + tid + k * 512;    // coalesced
        int d = -1, s = 0;
        if (e < E) {
            s = ei[e];
            d = ei[E + e];
            if ((unsigned)s < (unsigned)n && (unsigned)d < (unsigned)n)
                atomicAdd(&cnt[d / GN], 1);
            else d = -1;
        }
        sreg[k] = s; dreg[k] = d;
    }
    __syncthreads();
    { int c = cnt[tid]; cur[tid] = c ? atomicAdd(&gcursor[tid], c) : 0; }
    __syncthreads();
#pragma unroll
    for (int k = 0; k < NE; ++k) {
        int d = dreg[k];
        if (d >= 0) {
            int g = d / GN;
            int w = atomicAdd(&cur[g], 1);
            if (w < (g + 1) * CAP)   // capacity guard: drop -> loud absmax fail, no corruption
                pairs[w] = ((unsigned)(d - g * GN) << SRC_BITS) | (unsigned)sreg[k];
        }
    }
}

// one 512-thread block per group: LDS-stage pairs, hist, scan -> rowStart/rowEnd/dinv/z,
// then scatter srclist within the group's window
__global__ __launch_bounds__(512) void k_build(const int* __restrict__ gcursor,
                                               const unsigned* __restrict__ pairs,
                                               const float2* __restrict__ x2,
                                               int* __restrict__ rowStart, int* __restrict__ rowEnd,
                                               int* __restrict__ srclist, float* __restrict__ dinv,
                                               float2* __restrict__ z, int n, int GN) {
    __shared__ unsigned pl[CAP];
    __shared__ int cnt[512];
    __shared__ int cur[512];
    int g = blockIdx.x;
    int t = threadIdx.x;
    int gbeg = g * CAP;
    int gend = gcursor[g];
    int cape = gbeg + CAP;
    if (gend > cape) gend = cape;
    int m = gend - gbeg;
    cnt[t] = 0;
    __syncthreads();
    for (int k = t; k < m; k += 512) {
        unsigned v = pairs[gbeg + k];
        pl[k] = v;
        atomicAdd(&cnt[(v >> SRC_BITS) & 511], 1);
    }
    __syncthreads();
    int c = cnt[t];
    for (int off = 1; off < 512; off <<= 1) {
        int add = (t >= off) ? cnt[t - off] : 0;
        __syncthreads();
        cnt[t] += add;
        __syncthreads();
    }
    int excl = cnt[t] - c;
    int node = g * GN + t;
    if (t < GN && node < n) {
        int st = gbeg + excl;
        rowStart[node] = st;
        rowEnd[node] = st + c;
        float di = rsqrtf(1.0f + (float)c);
        dinv[node] = di;
        float2 xv = x2[node];
        z[node] = make_float2(xv.x * di, xv.y * di);
    }
    cur[t] = excl;
    __syncthreads();
    for (int k = t; k < m; k += 512) {
        unsigned v = pl[k];
        int dl = (v >> SRC_BITS) & 511;
        int pos = atomicAdd(&cur[dl], 1);
        srclist[gbeg + pos] = (int)(v & SRC_MASK);
    }
}

// ---------------- GCN compute ----------------

// conv1 aggregation, one LANE per node (no cross-lane reduce):
// agg[i] = z[i] + sum_{s->i} z[s]
__global__ __launch_bounds__(256) void k_gather2f(const int* __restrict__ rowStart,
                                                  const int* __restrict__ rowEnd,
                                                  const int* __restrict__ srclist,
                                                  const float2* __restrict__ z,
                                                  float2* __restrict__ agg, int n) {
    int w = blockIdx.x * 256 + threadIdx.x;
    if (w >= n) return;
    int e = rowStart[w], end = rowEnd[w];
    float ax = 0.f, ay = 0.f;
    int s = (e < end) ? srclist[e] : 0;   // 1-deep prefetch
    while (e < end) {
        int sc = s;
        ++e;
        if (e < end) s = srclist[e];
        float2 v = z[sc];
        ax += v.x; ay += v.y;
    }
    float2 v = z[w];   // self-loop
    agg[w] = make_float2(ax + v.x, ay + v.y);
}

// h1 = relu(dinv*(agg@W1) + b1); y = bf16((h1 @ W2) * dinv)
__global__ void k_mid1(const float2* __restrict__ agg, const float* __restrict__ dinv,
                       const float* __restrict__ W1, const float* __restrict__ b1,
                       const float* __restrict__ W2, unsigned short* __restrict__ y_bf, int n) {
    __shared__ float sW[1024];
    __shared__ float sh[8][33];
    int tid = threadIdx.x;
    for (int k = tid; k < 1024; k += 256) sW[k] = W2[k];
    int ln = tid >> 5, f = tid & 31;
    int i = blockIdx.x * 8 + ln;
    float h = 0.f, di = 0.f;
    if (i < n) {
        di = dinv[i];
        float2 a = agg[i];
        h = di * (a.x * W1[f] + a.y * W1[32 + f]) + b1[f];
        h = h > 0.f ? h : 0.f;
    }
    sh[ln][f] = h;
    __syncthreads();
    if (i < n) {
        float acc = 0.f;
#pragma unroll
        for (int k = 0; k < 32; ++k) acc += sh[ln][k] * sW[k * 32 + f];
        y_bf[(size_t)i * 32 + f] = f2bf(acc * di);
    }
}

// conv2 gather, 4 lanes per node, each lane owns one 16B quad of the 64B bf16 row;
// serial edge loop with 1-deep srclist prefetch; NO cross-lane reduce.
__global__ __launch_bounds__(256) void k_gather_rows(const int* __restrict__ rowStart,
                                                     const int* __restrict__ rowEnd,
                                                     const int* __restrict__ srclist,
                                                     const uint4* __restrict__ y4,
                                                     float4* __restrict__ acc4, int n) {
    int w = blockIdx.x * 64 + (threadIdx.x >> 2);
    int q = threadIdx.x & 3;
    if (w >= n) return;
    int e = rowStart[w], end = rowEnd[w];
    float a0 = 0.f, a1 = 0.f, a2 = 0.f, a3 = 0.f, a4 = 0.f, a5 = 0.f, a6 = 0.f, a7 = 0.f;
    int s = (e < end) ? srclist[e] : 0;   // 1-deep prefetch (4 lanes share addr -> broadcast)
    while (e < end) {
        int sc = s;
        ++e;
        if (e < end) s = srclist[e];
        uint4 v = y4[(size_t)sc * 4 + q];
        a0 += bf2f_lo(v.x); a1 += bf2f_hi(v.x);
        a2 += bf2f_lo(v.y); a3 += bf2f_hi(v.y);
        a4 += bf2f_lo(v.z); a5 += bf2f_hi(v.z);
        a6 += bf2f_lo(v.w); a7 += bf2f_hi(v.w);
    }
    uint4 v = y4[(size_t)w * 4 + q];   // self-loop
    a0 += bf2f_lo(v.x); a1 += bf2f_hi(v.x);
    a2 += bf2f_lo(v.y); a3 += bf2f_hi(v.y);
    a4 += bf2f_lo(v.z); a5 += bf2f_hi(v.z);
    a6 += bf2f_lo(v.w); a7 += bf2f_hi(v.w);
    size_t b = (size_t)w * 8 + q * 2;
    acc4[b]     = make_float4(a0, a1, a2, a3);
    acc4[b + 1] = make_float4(a4, a5, a6, a7);
}

// h2 = relu(dinv*acc + b2); h3 = relu(h2 @ Wf1 + bf1); out = h3 . Wf2 + bf2
__global__ void k_final(const float* __restrict__ acc, const float* __restrict__ dinv,
                        const float* __restrict__ b2, const float* __restrict__ Wf1,
                        const float* __restrict__ bf1, const float* __restrict__ Wf2,
                        const float* __restrict__ bf2, float* __restrict__ out, int n) {
    __shared__ float sW[1024];
    __shared__ float sh[8][33];
    int tid = threadIdx.x;
    for (int k = tid; k < 1024; k += 256) sW[k] = Wf1[k];
    int ln = tid >> 5, f = tid & 31;
    int i = blockIdx.x * 8 + ln;
    float h = 0.f;
    if (i < n) {
        h = dinv[i] * acc[(size_t)i * 32 + f] + b2[f];
        h = h > 0.f ? h : 0.f;
    }
    sh[ln][f] = h;
    __syncthreads();
    float p = 0.f;
    if (i < n) {
        float a = bf1[f];
#pragma unroll
        for (int k = 0; k < 32; ++k) a += sh[ln][k] * sW[k * 32 + f];
        a = a > 0.f ? a : 0.f;
        p = a * Wf2[f];
    }
#pragma unroll
    for (int m = 16; m >= 1; m >>= 1) p += __shfl_xor(p, m, 64);
    if (f == 0 && i < n) out[i] = p + bf2[0];
}

// ---------------- launch ----------------

extern "C" void kernel_launch(void* const* d_in, const int* in_sizes, int n_in,
                              void* d_out, int out_size, void* d_ws, size_t ws_size,
                              hipStream_t stream) {
    const float* x   = (const float*)d_in[0];
    const int*   ei  = (const int*)d_in[1];
    const float* W1  = (const float*)d_in[2];
    const float* b1  = (const float*)d_in[3];
    const float* W2  = (const float*)d_in[4];
    const float* b2  = (const float*)d_in[5];
    const float* Wf1 = (const float*)d_in[6];
    const float* bf1 = (const float*)d_in[7];
    const float* Wf2 = (const float*)d_in[8];
    const float* bf2 = (const float*)d_in[9];
    float* out = (float*)d_out;

    int n = in_sizes[0] / 2;   // x is [N,2]; n=100000 (<=131072)
    int E = in_sizes[1] / 2;   // edge_index is [2,E]
    int GN = (n + NGRP - 1) / NGRP;   // 196 nodes per group

    // workspace layout (float offsets; all even -> float2/uint4 alignment holds)
    float* wsf = (float*)d_ws;
    int*    srclist  = (int*)wsf;                          // NGRP*CAP ints
    size_t  o = (size_t)NGRP * CAP;
    int*    rowStart = (int*)(wsf + o);     o += n;        // n
    int*    rowEnd   = (int*)(wsf + o);     o += n;        // n
    float*  dinv     = wsf + o;             o += n;        // n
    float2* z        = (float2*)(wsf + o);  o += 2 * (size_t)n;   // n float2
    float2* agg      = (float2*)(wsf + o);  o += 2 * (size_t)n;   // n float2
    int*    gcursor  = (int*)(wsf + o);     o += NGRP;     // 512
    o = (o + 3) & ~(size_t)3;                              // 16B align
    float*  acc      = wsf + o;             o += 32 * (size_t)n;  // 32n floats
    unsigned short* y_bf = (unsigned short*)(wsf + o);     // 32n bf16 (16n floats)
    // pairs (NGRP*CAP u32 = 13.6MB) aliases acc + head of y_bf (19.2MB total);
    // consumed by k_build before y_bf (mid1) or acc (gather_rows) are written.
    unsigned* pairs = (unsigned*)acc;

    const int B = 256;
    int nblk = (E + EPB - 1) / EPB;

    // CSR build — zero per-edge global atomics, single ei read
    k_init<<<1, NGRP, 0, stream>>>(gcursor);
    k_partition<<<nblk, 512, 0, stream>>>(ei, gcursor, pairs, E, n, GN);
    k_build<<<NGRP, 512, 0, stream>>>(gcursor, pairs, (const float2*)x, rowStart, rowEnd,
                                      srclist, dinv, z, n, GN);

    // conv1: per-lane 2-feature aggregation, then fused (agg@W1 -> relu -> @W2 -> scale)
    k_gather2f<<<(n + 255) / 256, B, 0, stream>>>(rowStart, rowEnd, srclist, z, agg, n);
    k_mid1<<<(n + 7) / 8, B, 0, stream>>>(agg, dinv, W1, b1, W2, y_bf, n);

    // conv2: per-lane-quad full-row gather (no shuffles)
    k_gather_rows<<<(n + 63) / 64, B, 0, stream>>>(rowStart, rowEnd, srclist,
                                                   (const uint4*)y_bf, (float4*)acc, n);

    // conv2 finalize + MLP head
    k_final<<<(n + 7) / 8, B, 0, stream>>>(acc, dinv, b2, Wf1, bf1, Wf2, bf2, out, n);
}

// Round 11
// 174.531 us; speedup vs baseline: 1.2119x; 1.0301x over previous
//
#include <hip/hip_runtime.h>

#define NGRP 512        // dst-range groups; requires n <= 131072 (SRC_BITS) and GN <= 512
#define CAP  6656       // per-group edge capacity (E/NGRP=6250 + 5 sigma)
#define EPB  8192       // edges per partition block
#define NE   16         // edges register-cached per thread (EPB/512)
#define SRC_BITS 17
#define SRC_MASK 0x1FFFF

// ---- bf16 helpers (manual, RNE) ----
static __device__ __forceinline__ unsigned short f2bf(float f) {
    unsigned u = __float_as_uint(f);
    return (unsigned short)((u + 0x7FFFu + ((u >> 16) & 1u)) >> 16);
}
static __device__ __forceinline__ float bf2f_lo(unsigned u) { return __uint_as_float(u << 16); }
static __device__ __forceinline__ float bf2f_hi(unsigned u) { return __uint_as_float(u & 0xFFFF0000u); }

// ---------------- CSR build ----------------

__global__ void k_init(int* gcursor) {
    gcursor[threadIdx.x] = threadIdx.x * CAP;   // 512 threads
}

// single global read of ei: register-cache NE edges/thread across hist+scatter passes
__global__ __launch_bounds__(512) void k_partition(const int* __restrict__ ei, int* gcursor,
                                                   unsigned* __restrict__ pairs,
                                                   int E, int n, int GN) {
    __shared__ int cnt[NGRP];
    __shared__ int cur[NGRP];
    int tid = threadIdx.x;
    cnt[tid] = 0;
    __syncthreads();
    int base = blockIdx.x * EPB;
    int sreg[NE], dreg[NE];
#pragma unroll
    for (int k = 0; k < NE; ++k) {
        int e = base + tid + k * 512;    // coalesced
        int d = -1, s = 0;
        if (e < E) {
            s = ei[e];
            d = ei[E + e];
            if ((unsigned)s < (unsigned)n && (unsigned)d < (unsigned)n)
                atomicAdd(&cnt[d / GN], 1);
            else d = -1;
        }
        sreg[k] = s; dreg[k] = d;
    }
    __syncthreads();
    { int c = cnt[tid]; cur[tid] = c ? atomicAdd(&gcursor[tid], c) : 0; }
    __syncthreads();
#pragma unroll
    for (int k = 0; k < NE; ++k) {
        int d = dreg[k];
        if (d >= 0) {
            int g = d / GN;
            int w = atomicAdd(&cur[g], 1);
            if (w < (g + 1) * CAP)   // capacity guard: drop -> loud absmax fail, no corruption
                pairs[w] = ((unsigned)(d - g * GN) << SRC_BITS) | (unsigned)sreg[k];
        }
    }
}

// one 512-thread block per group: LDS-stage pairs, hist, scan -> rowStart/rowEnd/dinv/z,
// then scatter srclist within the group's window
__global__ __launch_bounds__(512) void k_build(const int* __restrict__ gcursor,
                                               const unsigned* __restrict__ pairs,
                                               const float2* __restrict__ x2,
                                               int* __restrict__ rowStart, int* __restrict__ rowEnd,
                                               int* __restrict__ srclist, float* __restrict__ dinv,
                                               float2* __restrict__ z, int n, int GN) {
    __shared__ unsigned pl[CAP];
    __shared__ int cnt[512];
    __shared__ int cur[512];
    int g = blockIdx.x;
    int t = threadIdx.x;
    int gbeg = g * CAP;
    int gend = gcursor[g];
    int cape = gbeg + CAP;
    if (gend > cape) gend = cape;
    int m = gend - gbeg;
    cnt[t] = 0;
    __syncthreads();
    for (int k = t; k < m; k += 512) {
        unsigned v = pairs[gbeg + k];
        pl[k] = v;
        atomicAdd(&cnt[(v >> SRC_BITS) & 511], 1);
    }
    __syncthreads();
    int c = cnt[t];
    for (int off = 1; off < 512; off <<= 1) {
        int add = (t >= off) ? cnt[t - off] : 0;
        __syncthreads();
        cnt[t] += add;
        __syncthreads();
    }
    int excl = cnt[t] - c;
    int node = g * GN + t;
    if (t < GN && node < n) {
        int st = gbeg + excl;
        rowStart[node] = st;
        rowEnd[node] = st + c;
        float di = rsqrtf(1.0f + (float)c);
        dinv[node] = di;
        float2 xv = x2[node];
        z[node] = make_float2(xv.x * di, xv.y * di);
    }
    cur[t] = excl;
    __syncthreads();
    for (int k = t; k < m; k += 512) {
        unsigned v = pl[k];
        int dl = (v >> SRC_BITS) & 511;
        int pos = atomicAdd(&cur[dl], 1);
        srclist[gbeg + pos] = (int)(v & SRC_MASK);
    }
}

// ---------------- GCN compute ----------------

// conv1 aggregation, one LANE per node, 4-deep unrolled independent loads
__global__ __launch_bounds__(256) void k_gather2f(const int* __restrict__ rowStart,
                                                  const int* __restrict__ rowEnd,
                                                  const int* __restrict__ srclist,
                                                  const float2* __restrict__ z,
                                                  float2* __restrict__ agg, int n) {
    int w = blockIdx.x * 256 + threadIdx.x;
    if (w >= n) return;
    int e = rowStart[w], end = rowEnd[w];
    float ax = 0.f, ay = 0.f;
    for (; e + 4 <= end; e += 4) {
        int s0 = srclist[e], s1 = srclist[e + 1], s2 = srclist[e + 2], s3 = srclist[e + 3];
        float2 v0 = z[s0], v1 = z[s1], v2 = z[s2], v3 = z[s3];
        ax += v0.x + v1.x + v2.x + v3.x;
        ay += v0.y + v1.y + v2.y + v3.y;
    }
    for (; e < end; ++e) {
        float2 v = z[srclist[e]];
        ax += v.x; ay += v.y;
    }
    float2 v = z[w];   // self-loop
    agg[w] = make_float2(ax + v.x, ay + v.y);
}

// h1 = relu(dinv*(agg@W1) + b1); y = bf16((h1 @ W2) * dinv) into two feature planes
__global__ void k_mid1(const float2* __restrict__ agg, const float* __restrict__ dinv,
                       const float* __restrict__ W1, const float* __restrict__ b1,
                       const float* __restrict__ W2, unsigned short* __restrict__ y0,
                       unsigned short* __restrict__ y1, int n) {
    __shared__ float sW[1024];
    __shared__ float sh[8][33];
    int tid = threadIdx.x;
    for (int k = tid; k < 1024; k += 256) sW[k] = W2[k];
    int ln = tid >> 5, f = tid & 31;
    int i = blockIdx.x * 8 + ln;
    float h = 0.f, di = 0.f;
    if (i < n) {
        di = dinv[i];
        float2 a = agg[i];
        h = di * (a.x * W1[f] + a.y * W1[32 + f]) + b1[f];
        h = h > 0.f ? h : 0.f;
    }
    sh[ln][f] = h;
    __syncthreads();
    if (i < n) {
        float acc = 0.f;
#pragma unroll
        for (int k = 0; k < 32; ++k) acc += sh[ln][k] * sW[k * 32 + f];
        unsigned short* yp = (f < 16) ? y0 : y1;
        yp[(size_t)i * 16 + (f & 15)] = f2bf(acc * di);
    }
}

#define ACC8(v)                                        \
    a0 += bf2f_lo((v).x); a1 += bf2f_hi((v).x);        \
    a2 += bf2f_lo((v).y); a3 += bf2f_hi((v).y);        \
    a4 += bf2f_lo((v).z); a5 += bf2f_hi((v).z);        \
    a6 += bf2f_lo((v).w); a7 += bf2f_hi((v).w);

// conv2 gather over ONE 16-feat plane (3.2MB, per-XCD-L2-resident):
// 4 lanes/node = 2 deg-slots x 2 quads; 4-deep unrolled loads; one shfl_xor(2) merge.
__global__ __launch_bounds__(256) void k_gather_plane(const int* __restrict__ rowStart,
                                                      const int* __restrict__ rowEnd,
                                                      const int* __restrict__ srclist,
                                                      const uint4* __restrict__ yh,
                                                      float4* __restrict__ acc4, int n, int p) {
    int w = blockIdx.x * 64 + (threadIdx.x >> 2);
    if (w >= n) return;
    int slot = (threadIdx.x >> 1) & 1;
    int q = threadIdx.x & 1;
    int beg = rowStart[w], end = rowEnd[w];
    int deg = end - beg;
    int half = (deg + 1) >> 1;
    int e = beg + slot * half;
    int e1 = slot ? end : (beg + half);
    float a0 = 0.f, a1 = 0.f, a2 = 0.f, a3 = 0.f, a4 = 0.f, a5 = 0.f, a6 = 0.f, a7 = 0.f;
    for (; e + 4 <= e1; e += 4) {
        int s0 = srclist[e], s1 = srclist[e + 1], s2 = srclist[e + 2], s3 = srclist[e + 3];
        uint4 v0 = yh[(size_t)s0 * 2 + q];
        uint4 v1 = yh[(size_t)s1 * 2 + q];
        uint4 v2 = yh[(size_t)s2 * 2 + q];
        uint4 v3 = yh[(size_t)s3 * 2 + q];
        ACC8(v0); ACC8(v1); ACC8(v2); ACC8(v3);
    }
    for (; e < e1; ++e) {
        uint4 v = yh[(size_t)srclist[e] * 2 + q];
        ACC8(v);
    }
    if (slot == 0) {                     // self-loop
        uint4 v = yh[(size_t)w * 2 + q];
        ACC8(v);
    }
    a0 += __shfl_xor(a0, 2, 64);
    a1 += __shfl_xor(a1, 2, 64);
    a2 += __shfl_xor(a2, 2, 64);
    a3 += __shfl_xor(a3, 2, 64);
    a4 += __shfl_xor(a4, 2, 64);
    a5 += __shfl_xor(a5, 2, 64);
    a6 += __shfl_xor(a6, 2, 64);
    a7 += __shfl_xor(a7, 2, 64);
    if (slot == 0) {
        float4* dst = acc4 + (size_t)w * 8 + p * 4 + q * 2;
        dst[0] = make_float4(a0, a1, a2, a3);
        dst[1] = make_float4(a4, a5, a6, a7);
    }
}

// h2 = relu(dinv*acc + b2); h3 = relu(h2 @ Wf1 + bf1); out = h3 . Wf2 + bf2
__global__ void k_final(const float* __restrict__ acc, const float* __restrict__ dinv,
                        const float* __restrict__ b2, const float* __restrict__ Wf1,
                        const float* __restrict__ bf1, const float* __restrict__ Wf2,
                        const float* __restrict__ bf2, float* __restrict__ out, int n) {
    __shared__ float sW[1024];
    __shared__ float sh[8][33];
    int tid = threadIdx.x;
    for (int k = tid; k < 1024; k += 256) sW[k] = Wf1[k];
    int ln = tid >> 5, f = tid & 31;
    int i = blockIdx.x * 8 + ln;
    float h = 0.f;
    if (i < n) {
        h = dinv[i] * acc[(size_t)i * 32 + f] + b2[f];
        h = h > 0.f ? h : 0.f;
    }
    sh[ln][f] = h;
    __syncthreads();
    float p = 0.f;
    if (i < n) {
        float a = bf1[f];
#pragma unroll
        for (int k = 0; k < 32; ++k) a += sh[ln][k] * sW[k * 32 + f];
        a = a > 0.f ? a : 0.f;
        p = a * Wf2[f];
    }
#pragma unroll
    for (int m = 16; m >= 1; m >>= 1) p += __shfl_xor(p, m, 64);
    if (f == 0 && i < n) out[i] = p + bf2[0];
}

// ---------------- launch ----------------

extern "C" void kernel_launch(void* const* d_in, const int* in_sizes, int n_in,
                              void* d_out, int out_size, void* d_ws, size_t ws_size,
                              hipStream_t stream) {
    const float* x   = (const float*)d_in[0];
    const int*   ei  = (const int*)d_in[1];
    const float* W1  = (const float*)d_in[2];
    const float* b1  = (const float*)d_in[3];
    const float* W2  = (const float*)d_in[4];
    const float* b2  = (const float*)d_in[5];
    const float* Wf1 = (const float*)d_in[6];
    const float* bf1 = (const float*)d_in[7];
    const float* Wf2 = (const float*)d_in[8];
    const float* bf2 = (const float*)d_in[9];
    float* out = (float*)d_out;

    int n = in_sizes[0] / 2;   // x is [N,2]; n=100000 (<=131072)
    int E = in_sizes[1] / 2;   // edge_index is [2,E]
    int GN = (n + NGRP - 1) / NGRP;   // 196 nodes per group

    // workspace layout (float offsets; all even -> float2/uint4 alignment holds)
    float* wsf = (float*)d_ws;
    int*    srclist  = (int*)wsf;                          // NGRP*CAP ints
    size_t  o = (size_t)NGRP * CAP;
    int*    rowStart = (int*)(wsf + o);     o += n;        // n
    int*    rowEnd   = (int*)(wsf + o);     o += n;        // n
    float*  dinv     = wsf + o;             o += n;        // n
    float2* z        = (float2*)(wsf + o);  o += 2 * (size_t)n;   // n float2
    float2* agg      = (float2*)(wsf + o);  o += 2 * (size_t)n;   // n float2
    int*    gcursor  = (int*)(wsf + o);     o += NGRP;     // 512
    o = (o + 3) & ~(size_t)3;                              // 16B align
    float*  acc      = wsf + o;             o += 32 * (size_t)n;  // 32n floats
    unsigned short* y0 = (unsigned short*)(wsf + o);       // 16n bf16 (8n floats)
    unsigned short* y1 = y0 + (size_t)n * 16;              // 16n bf16
    // pairs (NGRP*CAP u32 = 13.6MB) aliases acc (+ head of y planes); consumed by
    // k_build before acc (gather_plane) or y planes (mid1) are written.
    unsigned* pairs = (unsigned*)acc;

    const int B = 256;
    int nblk = (E + EPB - 1) / EPB;

    // CSR build — zero per-edge global atomics, single ei read
    k_init<<<1, NGRP, 0, stream>>>(gcursor);
    k_partition<<<nblk, 512, 0, stream>>>(ei, gcursor, pairs, E, n, GN);
    k_build<<<NGRP, 512, 0, stream>>>(gcursor, pairs, (const float2*)x, rowStart, rowEnd,
                                      srclist, dinv, z, n, GN);

    // conv1: per-lane 2-feature aggregation (unrolled), then fused MLP to y planes
    k_gather2f<<<(n + 255) / 256, B, 0, stream>>>(rowStart, rowEnd, srclist, z, agg, n);
    k_mid1<<<(n + 7) / 8, B, 0, stream>>>(agg, dinv, W1, b1, W2, y0, y1, n);

    // conv2: two L2-resident plane gathers, serial-unrolled per lane
    k_gather_plane<<<(n + 63) / 64, B, 0, stream>>>(rowStart, rowEnd, srclist,
                                                    (const uint4*)y0, (float4*)acc, n, 0);
    k_gather_plane<<<(n + 63) / 64, B, 0, stream>>>(rowStart, rowEnd, srclist,
                                                    (const uint4*)y1, (float4*)acc, n, 1);

    // conv2 finalize + MLP head
    k_final<<<(n + 7) / 8, B, 0, stream>>>(acc, dinv, b2, Wf1, bf1, Wf2, bf2, out, n);
}